// Round 1
// baseline (556.075 us; speedup 1.0000x reference)
//
#include <hip/hip_runtime.h>
#include <hip/hip_fp16.h>

#define D 64

typedef unsigned long long ull;

// ---------------- fallback: atomic SpMM (guard path, unchanged) ----------------
__global__ __launch_bounds__(256) void spmm_atomic_kernel(
    const float* __restrict__ x,
    const int*   __restrict__ edge_row,
    const int*   __restrict__ edge_col,
    const float* __restrict__ edge_val,
    float*       __restrict__ out,
    int n_edges)
{
    const int gtid = blockIdx.x * blockDim.x + threadIdx.x;
    const int wave = gtid >> 6;
    const int lane = threadIdx.x & 63;
    if (wave >= n_edges) return;
    const int   r = edge_row[wave];
    const int   c = edge_col[wave];
    const float v = edge_val[wave];
    atomicAdd(&out[(size_t)r * D + lane], v * x[(size_t)c * D + lane]);
}

// ---------------- H: global histogram over key = (row<<3)|colslice ----------------
// 800K keys (3.2 MB) stay L2-resident; ~4 edges/key -> negligible atomic contention.
__global__ __launch_bounds__(256) void hist_kernel(
    const int* __restrict__ rows, const int* __restrict__ cols,
    int* __restrict__ hist, int n_edges)
{
    const int i = (blockIdx.x * 256 + threadIdx.x) * 4;
    if (i + 4 <= n_edges) {
        const int4 r = *(const int4*)(rows + i);
        const int4 c = *(const int4*)(cols + i);
        atomicAdd(&hist[(r.x << 3) | (c.x >> 14)], 1);
        atomicAdd(&hist[(r.y << 3) | (c.y >> 14)], 1);
        atomicAdd(&hist[(r.z << 3) | (c.z >> 14)], 1);
        atomicAdd(&hist[(r.w << 3) | (c.w >> 14)], 1);
    } else {
        for (int k = i; k < n_edges; ++k)
            atomicAdd(&hist[(rows[k] << 3) | (cols[k] >> 14)], 1);
    }
}

// ---------------- S1: per-4096-chunk exclusive scan + chunk sums ----------------
__global__ __launch_bounds__(1024) void scan1_kernel(
    const int* __restrict__ hist, int* __restrict__ keybase,
    int* __restrict__ sums, int nkeys)
{
    __shared__ int s[1024];
    const int t    = threadIdx.x;
    const int base = blockIdx.x * 4096 + t * 4;
    int4 v = make_int4(0, 0, 0, 0);
    if (base + 4 <= nkeys) {
        v = *(const int4*)(hist + base);
    } else {
        if (base + 0 < nkeys) v.x = hist[base + 0];
        if (base + 1 < nkeys) v.y = hist[base + 1];
        if (base + 2 < nkeys) v.z = hist[base + 2];
        if (base + 3 < nkeys) v.w = hist[base + 3];
    }
    const int sum = v.x + v.y + v.z + v.w;
    s[t] = sum;
    for (int off = 1; off < 1024; off <<= 1) {
        __syncthreads();
        const int w = (t >= off) ? s[t - off] : 0;
        __syncthreads();
        s[t] += w;
    }
    const int excl = s[t] - sum;
    if (t == 1023) sums[blockIdx.x] = s[t];
    int4 o;
    o.x = excl;
    o.y = o.x + v.x;
    o.z = o.y + v.y;
    o.w = o.z + v.z;
    if (base + 4 <= nkeys) {
        *(int4*)(keybase + base) = o;
    } else {
        if (base + 0 < nkeys) keybase[base + 0] = o.x;
        if (base + 1 < nkeys) keybase[base + 1] = o.y;
        if (base + 2 < nkeys) keybase[base + 2] = o.z;
        if (base + 3 < nkeys) keybase[base + 3] = o.w;
    }
}

// ---------------- S2: exclusive scan over chunk sums (nblk <= 256) ----------------
__global__ __launch_bounds__(256) void scan2_kernel(int* __restrict__ sums, int n)
{
    __shared__ int s[256];
    const int t = threadIdx.x;
    const int v = (t < n) ? sums[t] : 0;
    s[t] = v;
    for (int off = 1; off < 256; off <<= 1) {
        __syncthreads();
        const int w = (t >= off) ? s[t - off] : 0;
        __syncthreads();
        s[t] += w;
    }
    if (t < n) sums[t] = s[t] - v;
}

// ---------------- S3: add-back + cursor copy + sentinel ----------------
__global__ __launch_bounds__(256) void scan3_kernel(
    int* __restrict__ keybase, int* __restrict__ cursor,
    const int* __restrict__ sums, int nkeys, int n_edges)
{
    const int base = (blockIdx.x * 256 + threadIdx.x) * 4;
    const int add  = sums[blockIdx.x >> 2];   // 1024-elem block within one 4096 chunk
    if (base + 4 <= nkeys) {
        int4 v = *(const int4*)(keybase + base);
        v.x += add; v.y += add; v.z += add; v.w += add;
        *(int4*)(keybase + base) = v;
        *(int4*)(cursor + base)  = v;
    } else {
        for (int k = base; k < nkeys; ++k) {
            const int v = keybase[k] + add;
            keybase[k] = v;
            cursor[k]  = v;
        }
    }
    if (blockIdx.x == 0 && threadIdx.x == 0) keybase[nkeys] = n_edges;
}

// ---------------- SC: atomic-cursor scatter -> recs[(row,colslice)-sorted] -------
// rec = [ val:f32 (hi32) | col:bits0-16 ]. Scattered 8B writes into 25.6MB are
// absorbed/merged by L2 (write-allocate), evicted ~once -> ~26MB HBM writes.
__global__ __launch_bounds__(256) void scatter_kernel(
    const int* __restrict__ rows, const int* __restrict__ cols,
    const float* __restrict__ vals,
    int* __restrict__ cursor, ull* __restrict__ recs, int n_edges)
{
    const int i = (blockIdx.x * 256 + threadIdx.x) * 4;
    if (i + 4 <= n_edges) {
        const int4   r = *(const int4*)(rows + i);
        const int4   c = *(const int4*)(cols + i);
        const float4 v = *(const float4*)(vals + i);
        int p;
        p = atomicAdd(&cursor[(r.x << 3) | (c.x >> 14)], 1);
        recs[p] = ((ull)__float_as_uint(v.x) << 32) | (unsigned)c.x;
        p = atomicAdd(&cursor[(r.y << 3) | (c.y >> 14)], 1);
        recs[p] = ((ull)__float_as_uint(v.y) << 32) | (unsigned)c.y;
        p = atomicAdd(&cursor[(r.z << 3) | (c.z >> 14)], 1);
        recs[p] = ((ull)__float_as_uint(v.z) << 32) | (unsigned)c.z;
        p = atomicAdd(&cursor[(r.w << 3) | (c.w >> 14)], 1);
        recs[p] = ((ull)__float_as_uint(v.w) << 32) | (unsigned)c.w;
    } else {
        for (int k = i; k < n_edges; ++k) {
            const int p = atomicAdd(&cursor[(rows[k] << 3) | (cols[k] >> 14)], 1);
            recs[p] = ((ull)__float_as_uint(vals[k]) << 32) | (unsigned)cols[k];
        }
    }
}

// ---------------- P0: x -> fp16 ----------------
__global__ void tohalf_kernel(const float* __restrict__ x,
                              __half2* __restrict__ xh2, int n4)
{
    for (int i = blockIdx.x * blockDim.x + threadIdx.x; i < n4;
         i += gridDim.x * blockDim.x) {
        const float4 v = ((const float4*)x)[i];
        xh2[2 * i + 0] = __floats2half2_rn(v.x, v.y);
        xh2[2 * i + 1] = __floats2half2_rn(v.z, v.w);
    }
}

// ---------------- K6: split-wave half2 CSR SpMM, 16 edges in flight ----------------
// Lanes 0-31 take even edges, 32-63 odd edges; each lane loads a __half2 (dword),
// so one gather instruction covers 2 edges (2x MLP vs round-0's 8). Masked full
// batches keep the 8-deep pipeline full on tails. Halves combined via shfl_xor(32).
__global__ __launch_bounds__(256, 8) void spmm_csr_half2_kernel(
    const __half2* __restrict__ xh2,
    const int*     __restrict__ keybase,
    const ull*     __restrict__ recs,
    float*         __restrict__ out,
    int n_nodes)
{
    const int row = blockIdx.x * 4 + (threadIdx.x >> 6);
    if (row >= n_nodes) return;
    const int lane = threadIdx.x & 63;
    const int half = lane >> 5;
    const int fl   = lane & 31;

    const int s = keybase[row << 3];
    const int e = keybase[(row << 3) + 8];
    float accx = 0.f, accy = 0.f;

    int j = s;
    // full batches: 16 edges, 8 gathers in flight
    for (; j + 16 <= e; j += 16) {
        float vv[8]; int aa[8];
        #pragma unroll
        for (int k = 0; k < 8; ++k) {
            const ull rec = recs[j + 2 * k + half];
            vv[k] = __uint_as_float((unsigned)(rec >> 32));
            aa[k] = ((int)((unsigned)rec & 0x1FFFF) << 5) + fl;
        }
        __half2 hv[8];
        #pragma unroll
        for (int k = 0; k < 8; ++k) hv[k] = xh2[aa[k]];   // 8 gathers = 16 edges ISSUED
        __builtin_amdgcn_sched_barrier(0);                // ...kept in flight
        #pragma unroll
        for (int k = 0; k < 8; ++k) {
            const float2 xf = __half22float2(hv[k]);
            accx = fmaf(vv[k], xf.x, accx);
            accy = fmaf(vv[k], xf.y, accy);
        }
    }
    // single masked batch for the tail: pipeline stays 8-deep
    if (j < e) {
        const int safe = e - 1;
        float vv[8]; int aa[8];
        #pragma unroll
        for (int k = 0; k < 8; ++k) {
            const int  idx = j + 2 * k + half;
            const bool ok  = idx < e;
            const ull  rec = recs[ok ? idx : safe];
            vv[k] = ok ? __uint_as_float((unsigned)(rec >> 32)) : 0.f;
            aa[k] = ((int)((unsigned)rec & 0x1FFFF) << 5) + fl;
        }
        __half2 hv[8];
        #pragma unroll
        for (int k = 0; k < 8; ++k) hv[k] = xh2[aa[k]];
        __builtin_amdgcn_sched_barrier(0);
        #pragma unroll
        for (int k = 0; k < 8; ++k) {
            const float2 xf = __half22float2(hv[k]);
            accx = fmaf(vv[k], xf.x, accx);
            accy = fmaf(vv[k], xf.y, accy);
        }
    }

    accx += __shfl_xor(accx, 32);
    accy += __shfl_xor(accy, 32);
    if (half == 0) {
        float2 o; o.x = accx; o.y = accy;
        ((float2*)out)[(size_t)row * 32 + fl] = o;
    }
}

static inline size_t align16(size_t v) { return (v + 15) & ~(size_t)15; }

extern "C" void kernel_launch(void* const* d_in, const int* in_sizes, int n_in,
                              void* d_out, int out_size, void* d_ws, size_t ws_size,
                              hipStream_t stream)
{
    // setup_inputs order: t, x, edge_row, edge_col, edge_val
    const float* x        = (const float*)d_in[1];
    const int*   edge_row = (const int*)d_in[2];
    const int*   edge_col = (const int*)d_in[3];
    const float* edge_val = (const float*)d_in[4];
    float*       out      = (float*)d_out;

    const int n_edges = in_sizes[2];
    const int n_nodes = out_size / D;
    const int nkeys   = n_nodes * 8;              // key = (row<<3)|colslice
    const int nscan1  = (nkeys + 4095) >> 12;     // 4096 elems per scan1 block

    // workspace carve
    const size_t off_recs = 0;                                         // n_edges*8
    const size_t off_xh   = align16(off_recs + (size_t)n_edges * 8);   // n_nodes*128
    const size_t off_keyb = align16(off_xh + (size_t)n_nodes * D * 2); // (nkeys+1)*4
    const size_t off_cur  = align16(off_keyb + (size_t)(nkeys + 1) * 4);
    const size_t off_hist = align16(off_cur + (size_t)nkeys * 4);
    const size_t off_sums = align16(off_hist + (size_t)nkeys * 4);
    const size_t ws_needed = off_sums + (size_t)nscan1 * 4;

    if (ws_size < ws_needed || n_nodes > (1 << 17) || n_edges < 1 || nscan1 > 256) {
        hipMemsetAsync(out, 0, (size_t)out_size * sizeof(float), stream);
        const int n_blocks = (n_edges + 3) / 4;
        spmm_atomic_kernel<<<n_blocks, 256, 0, stream>>>(
            x, edge_row, edge_col, edge_val, out, n_edges);
        return;
    }

    char*   ws      = (char*)d_ws;
    ull*    recs    = (ull*)(ws + off_recs);
    __half* xh      = (__half*)(ws + off_xh);
    int*    keybase = (int*)(ws + off_keyb);
    int*    cursor  = (int*)(ws + off_cur);
    int*    hist    = (int*)(ws + off_hist);
    int*    sums    = (int*)(ws + off_sums);

    const int n_eblk = (n_edges + 1023) / 1024;   // 4 edges/thread

    hipMemsetAsync(hist, 0, (size_t)nkeys * 4, stream);
    // H: histogram of (row,colslice)
    hist_kernel<<<n_eblk, 256, 0, stream>>>(edge_row, edge_col, hist, n_edges);
    // S1..S3: exclusive scan -> keybase (kept) + cursor (consumed by scatter)
    scan1_kernel<<<nscan1, 1024, 0, stream>>>(hist, keybase, sums, nkeys);
    scan2_kernel<<<1, 256, 0, stream>>>(sums, nscan1);
    scan3_kernel<<<(nkeys + 1023) / 1024, 256, 0, stream>>>(
        keybase, cursor, sums, nkeys, n_edges);
    // SC: scatter edges to (row,colslice)-sorted recs
    scatter_kernel<<<n_eblk, 256, 0, stream>>>(
        edge_row, edge_col, edge_val, cursor, recs, n_edges);
    // P0: x -> fp16
    const int n4 = (n_nodes * D) / 4;
    tohalf_kernel<<<2048, 256, 0, stream>>>(x, (__half2*)xh, n4);
    // K6: split-wave half2 SpMM (offsets read directly from keybase[8*row])
    spmm_csr_half2_kernel<<<(n_nodes + 3) / 4, 256, 0, stream>>>(
        (const __half2*)xh, keybase, recs, out, n_nodes);
}